// Round 7
// baseline (83.108 us; speedup 1.0000x reference)
//
#include <hip/hip_runtime.h>

#define Oo    32
#define F2    4096
#define NTILE 256            // pixel tiles of 16
#define Qn    4              // batch quarters
#define BPQ   8              // batches per block
#define GRID  (NTILE * Qn)   // 1024
#define SLOTS GRID
#define NTOT  (32 * F2)

typedef _Float16 h2 __attribute__((ext_vector_type(2)));

#if __has_builtin(__builtin_amdgcn_fdot2)
#define DOT2(a, b, c) __builtin_amdgcn_fdot2((a), (b), (c), false)
#else
__device__ __forceinline__ float DOT2(h2 a, h2 b, float c) {
    return c + (float)a.x * (float)b.x + (float)a.y * (float)b.y;
}
#endif

__device__ __forceinline__ h2 bch2(unsigned u) { return __builtin_bit_cast(h2, u); }

// Round-3 structure (passed post-timing) at 4 blocks/CU.
// Block: 256 thr = (og:16) x (f:16); grid 1024 = (quarter:4) x (tile:256).
// Thread: 2 output channels (og, og+16), 8 batches of its quarter, 1 pixel.
// Weights: 2x36 h2 in regs, loaded once, 64B-coalesced per (o,p).
// Patches: f16, double-buffered LDS (4.6KB), one barrier/iter; next batch
// prefetched into regs during compute. bid order q*256+tile => all quarters
// of a tile on the same XCD (1024 % 8 == 0); weights L3-resident after q=0.
__global__ __launch_bounds__(256, 4) void svconv_kernel(
    const float* __restrict__ x, const float* __restrict__ wgt,
    const float* __restrict__ bias, float* __restrict__ y,
    float* __restrict__ psum, float* __restrict__ psumsq)
{
    __shared__ __align__(16) _Float16 pat[2][16 * 72];

    const int tid  = threadIdx.x;
    const int f    = tid & 15;
    const int og   = tid >> 4;           // 0..15
    const int tile = blockIdx.x & (NTILE - 1);
    const int qtr  = blockIdx.x >> 8;
    const int fb   = tile * 16;
    const int col  = fb + f;
    const int h    = fb >> 6;
    const int w0   = fb & 63;

    // ---- weights for 2 output channels (og, og+16), packed f16 ----
    h2    w2[2][36];
    float bz[2];
#pragma unroll
    for (int j = 0; j < 2; ++j) {
        const int o = og + 16 * j;
        const float* wp = wgt + (size_t)(o * 72) * F2 + col;
#pragma unroll
        for (int q = 0; q < 36; ++q) {
            float a = wp[(2 * q) * F2];
            float b = wp[(2 * q + 1) * F2];
            h2 t; t.x = (_Float16)a; t.y = (_Float16)b;
            w2[j][q] = t;
        }
        bz[j] = bias[o * F2 + col];
    }

    // ---- patch-fill slots (batch-invariant): e = tid + k*256 over 1152 ----
    int xb[5];
#pragma unroll
    for (int k = 0; k < 5; ++k) {
        int e = tid + k * 256;
        if (e < 16 * 72) {
            int pix = e / 72, p = e - pix * 72;
            int c   = p / 9,  r = p - c * 9;
            int kh  = r / 3,  kw = r - kh * 3;
            int gh  = h + kh - 1;
            int gw  = w0 + pix + kw - 1;
            xb[k] = ((unsigned)gh < 64u && (unsigned)gw < 64u)
                        ? (c * 64 + gh) * 64 + gw : -1;
        } else {
            xb[k] = -2;
        }
    }

    float s0 = 0.f, ss0 = 0.f, s1 = 0.f, ss1 = 0.f;
    const int b0 = qtr * BPQ;

    // ---- prologue: stage batch b0 into buffer 0 ----
    {
        float r0[5];
#pragma unroll
        for (int k = 0; k < 5; ++k)
            r0[k] = (xb[k] >= 0) ? x[b0 * 32768 + xb[k]] : 0.f;
#pragma unroll
        for (int k = 0; k < 5; ++k)
            if (xb[k] != -2) pat[0][tid + k * 256] = (_Float16)r0[k];
    }
    __syncthreads();

    for (int bi = 0; bi < BPQ; ++bi) {
        const int b   = b0 + bi;
        const int cur = bi & 1;

        float r1[5];
        if (bi < BPQ - 1) {
#pragma unroll
            for (int k = 0; k < 5; ++k)
                r1[k] = (xb[k] >= 0) ? x[(b + 1) * 32768 + xb[k]] : 0.f;
        }

        const uint4* pv = (const uint4*)(&pat[cur][f * 72]);
        uint4 u[9];
#pragma unroll
        for (int q = 0; q < 9; ++q) u[q] = pv[q];

        float a0 = bz[0], a1 = bz[1];
#pragma unroll
        for (int q = 0; q < 9; ++q) {
            a0 = DOT2(w2[0][4 * q + 0], bch2(u[q].x), a0);
            a0 = DOT2(w2[0][4 * q + 1], bch2(u[q].y), a0);
            a0 = DOT2(w2[0][4 * q + 2], bch2(u[q].z), a0);
            a0 = DOT2(w2[0][4 * q + 3], bch2(u[q].w), a0);
            a1 = DOT2(w2[1][4 * q + 0], bch2(u[q].x), a1);
            a1 = DOT2(w2[1][4 * q + 1], bch2(u[q].y), a1);
            a1 = DOT2(w2[1][4 * q + 2], bch2(u[q].z), a1);
            a1 = DOT2(w2[1][4 * q + 3], bch2(u[q].w), a1);
        }

        y[(b * Oo + og) * F2 + col]      = a0;
        y[(b * Oo + og + 16) * F2 + col] = a1;
        s0 += a0; ss0 = fmaf(a0, a0, ss0);
        s1 += a1; ss1 = fmaf(a1, a1, ss1);

        if (bi < BPQ - 1) {
#pragma unroll
            for (int k = 0; k < 5; ++k)
                if (xb[k] != -2) pat[cur ^ 1][tid + k * 256] = (_Float16)r1[k];
        }
        __syncthreads();
    }

    // ---- BN partials (primary path only) ----
    if (psum != nullptr) {
#pragma unroll
        for (int d = 8; d >= 1; d >>= 1) {
            s0  += __shfl_down(s0,  d, 16);
            ss0 += __shfl_down(ss0, d, 16);
            s1  += __shfl_down(s1,  d, 16);
            ss1 += __shfl_down(ss1, d, 16);
        }
        if (f == 0) {
            const int slot = blockIdx.x;
            psum[og * SLOTS + slot]          = s0;
            psumsq[og * SLOTS + slot]        = ss0;
            psum[(og + 16) * SLOTS + slot]   = s1;
            psumsq[(og + 16) * SLOTS + slot] = ss1;
        }
    }
}

__global__ __launch_bounds__(256) void bnstats_kernel(
    const float* __restrict__ psum, const float* __restrict__ psumsq,
    const float* __restrict__ gamma, const float* __restrict__ beta,
    float* __restrict__ scsh)
{
    const int o = blockIdx.x;
    const int t = threadIdx.x;
    float s = 0.f, ss = 0.f;
#pragma unroll
    for (int i = 0; i < 4; ++i) {
        s  += psum[o * SLOTS + t + 256 * i];
        ss += psumsq[o * SLOTS + t + 256 * i];
    }
#pragma unroll
    for (int d = 32; d >= 1; d >>= 1) {
        s  += __shfl_down(s, d, 64);
        ss += __shfl_down(ss, d, 64);
    }
    __shared__ float ls[4], lss[4];
    int wv = t >> 6, ln = t & 63;
    if (ln == 0) { ls[wv] = s; lss[wv] = ss; }
    __syncthreads();
    if (t == 0) {
        float S   = (ls[0] + ls[1]) + (ls[2] + ls[3]);
        float SS  = (lss[0] + lss[1]) + (lss[2] + lss[3]);
        float mean = S / (float)NTOT;
        float var  = SS / (float)NTOT - mean * mean;
        float rstd = rsqrtf(var + 1e-5f);
        float scl  = gamma[o] * rstd;
        scsh[o]      = scl;
        scsh[Oo + o] = beta[o] - mean * scl;
    }
}

// ---- fallback stats path (tiny scratch): reduce y directly ----
__global__ __launch_bounds__(256) void bnreduce_y_kernel(
    const float* __restrict__ y, float* __restrict__ seg, float* __restrict__ segsq)
{
    const int o  = blockIdx.x >> 3;
    const int sg = blockIdx.x & 7;
    const int t  = threadIdx.x;
    float s = 0.f, ss = 0.f;
    for (int i = t; i < 4 * 1024; i += 256) {      // 4 batches x 1024 float4
        int b   = sg * 4 + (i >> 10);
        int fof = (i & 1023) * 4;
        float4 v = *(const float4*)(y + (size_t)(b * Oo + o) * F2 + fof);
        s  += (v.x + v.y) + (v.z + v.w);
        ss += v.x * v.x + v.y * v.y + v.z * v.z + v.w * v.w;
    }
#pragma unroll
    for (int d = 32; d >= 1; d >>= 1) {
        s  += __shfl_down(s, d, 64);
        ss += __shfl_down(ss, d, 64);
    }
    __shared__ float ls[4], lss[4];
    int wv = t >> 6, ln = t & 63;
    if (ln == 0) { ls[wv] = s; lss[wv] = ss; }
    __syncthreads();
    if (t == 0) {
        seg[blockIdx.x]   = (ls[0] + ls[1]) + (ls[2] + ls[3]);
        segsq[blockIdx.x] = (lss[0] + lss[1]) + (lss[2] + lss[3]);
    }
}

__global__ __launch_bounds__(256) void bnstats2_kernel(
    const float* __restrict__ seg, const float* __restrict__ segsq,
    const float* __restrict__ gamma, const float* __restrict__ beta,
    float* __restrict__ scsh)
{
    const int t = threadIdx.x;       // 256 = 32 o x 8 segments
    const int o = t >> 3, g = t & 7;
    float v  = seg[t];
    float vv = segsq[t];
#pragma unroll
    for (int d = 4; d >= 1; d >>= 1) {
        v  += __shfl_down(v,  d, 8);
        vv += __shfl_down(vv, d, 8);
    }
    if (g == 0) {
        float mean = v / (float)NTOT;
        float var  = vv / (float)NTOT - mean * mean;
        float rstd = rsqrtf(var + 1e-5f);
        float scl  = gamma[o] * rstd;
        scsh[o]      = scl;
        scsh[Oo + o] = beta[o] - mean * scl;
    }
}

__global__ __launch_bounds__(256) void bnapply_kernel(
    float* __restrict__ y, const float* __restrict__ scsh)
{
    int i = blockIdx.x * 256 + threadIdx.x;    // float4 index
    float4 v = ((const float4*)y)[i];
    int o = (i >> 10) & 31;                    // F2/4 = 1024 float4 per (b,o)
    float scl = scsh[o], sh = scsh[Oo + o];
    v.x = fmaf(v.x, scl, sh);
    v.y = fmaf(v.y, scl, sh);
    v.z = fmaf(v.z, scl, sh);
    v.w = fmaf(v.w, scl, sh);
    ((float4*)y)[i] = v;
}

extern "C" void kernel_launch(void* const* d_in, const int* in_sizes, int n_in,
                              void* d_out, int out_size, void* d_ws, size_t ws_size,
                              hipStream_t stream)
{
    const float* x     = (const float*)d_in[0];
    const float* wgt   = (const float*)d_in[1];
    const float* bias  = (const float*)d_in[2];
    const float* gamma = (const float*)d_in[3];
    const float* beta  = (const float*)d_in[4];
    float* y = (float*)d_out;

    const size_t need_primary = (size_t)(2 * Oo * SLOTS + 2 * Oo) * sizeof(float);

    if (ws_size >= need_primary) {
        float* psum   = (float*)d_ws;               // [Oo][SLOTS]
        float* psumsq = psum + Oo * SLOTS;          // [Oo][SLOTS]
        float* scsh   = psumsq + Oo * SLOTS;        // [2][Oo]
        svconv_kernel<<<GRID, 256, 0, stream>>>(x, wgt, bias, y, psum, psumsq);
        bnstats_kernel<<<Oo, 256, 0, stream>>>(psum, psumsq, gamma, beta, scsh);
        bnapply_kernel<<<NTOT * Oo / 4 / 256, 256, 0, stream>>>(y, scsh);
    } else {
        float* seg   = (float*)d_ws;                // [256]
        float* segsq = seg + 256;                   // [256]
        float* scsh  = segsq + 256;                 // [2][Oo]
        svconv_kernel<<<GRID, 256, 0, stream>>>(x, wgt, bias, y, nullptr, nullptr);
        bnreduce_y_kernel<<<256, 256, 0, stream>>>(y, seg, segsq);
        bnstats2_kernel<<<1, 256, 0, stream>>>(seg, segsq, gamma, beta, scsh);
        bnapply_kernel<<<NTOT * Oo / 4 / 256, 256, 0, stream>>>(y, scsh);
    }
}

// Round 8
// 77.502 us; speedup vs baseline: 1.0723x; 1.0723x over previous
//
#include <hip/hip_runtime.h>

#define Oo    32
#define F2    4096
#define NTILE 256            // pixel tiles of 16
#define Qn    4              // batch quarters
#define BPQ   8              // batches per block
#define GRID  (NTILE * Qn)   // 1024
#define SLOTS GRID
#define NTOT  (32 * F2)

typedef _Float16 h2 __attribute__((ext_vector_type(2)));

#if __has_builtin(__builtin_amdgcn_fdot2)
#define DOT2(a, b, c) __builtin_amdgcn_fdot2((a), (b), (c), false)
#else
__device__ __forceinline__ float DOT2(h2 a, h2 b, float c) {
    return c + (float)a.x * (float)b.x + (float)a.y * (float)b.y;
}
#endif

__device__ __forceinline__ h2 bch2(unsigned u) { return __builtin_bit_cast(h2, u); }

// Round-3 structure (passed post-timing 3x) at 4 blocks/CU via batch quartering.
// Block: 256 thr = (og:16) x (f:16); grid 1024 = (quarter:4) x (tile:256).
// Thread: 2 output channels (og, og+16), 8 batches of its quarter, 1 pixel.
// Weights: 2x36 h2 in regs, loaded once, 64B-coalesced per (o,p).
// Patches: f16, double-buffered LDS (4.6KB), one barrier/iter; next batch
// prefetched into regs during compute. bid = q*256+tile => same-tile quarters
// land on the same XCD (256 % 8 == 0) -> weight re-reads are L2 hits.
// launch_bounds: NO min-waves arg. Evidence: (256,4)/(1024,4) cap VGPR at 64,
// (512,2) at 88, (256,2) at 124; this kernel needs ~90 -> any ",4" spills
// ~48MB of scratch (round 7: WRITE 65MB, 84us). Natural allocation fits the
// grid-limited 4 waves/EU anyway.
__global__ __launch_bounds__(256) void svconv_kernel(
    const float* __restrict__ x, const float* __restrict__ wgt,
    const float* __restrict__ bias, float* __restrict__ y,
    float* __restrict__ psum, float* __restrict__ psumsq)
{
    __shared__ __align__(16) _Float16 pat[2][16 * 72];

    const int tid  = threadIdx.x;
    const int f    = tid & 15;
    const int og   = tid >> 4;           // 0..15
    const int tile = blockIdx.x & (NTILE - 1);
    const int qtr  = blockIdx.x >> 8;
    const int fb   = tile * 16;
    const int col  = fb + f;
    const int h    = fb >> 6;
    const int w0   = fb & 63;

    // ---- weights for 2 output channels (og, og+16), packed f16 ----
    h2    w2[2][36];
    float bz[2];
#pragma unroll
    for (int j = 0; j < 2; ++j) {
        const int o = og + 16 * j;
        const float* wp = wgt + (size_t)(o * 72) * F2 + col;
#pragma unroll
        for (int q = 0; q < 36; ++q) {
            float a = wp[(2 * q) * F2];
            float b = wp[(2 * q + 1) * F2];
            h2 t; t.x = (_Float16)a; t.y = (_Float16)b;
            w2[j][q] = t;
        }
        bz[j] = bias[o * F2 + col];
    }

    // ---- patch-fill slots (batch-invariant): e = tid + k*256 over 1152 ----
    int xb[5];
#pragma unroll
    for (int k = 0; k < 5; ++k) {
        int e = tid + k * 256;
        if (e < 16 * 72) {
            int pix = e / 72, p = e - pix * 72;
            int c   = p / 9,  r = p - c * 9;
            int kh  = r / 3,  kw = r - kh * 3;
            int gh  = h + kh - 1;
            int gw  = w0 + pix + kw - 1;
            xb[k] = ((unsigned)gh < 64u && (unsigned)gw < 64u)
                        ? (c * 64 + gh) * 64 + gw : -1;
        } else {
            xb[k] = -2;
        }
    }

    float s0 = 0.f, ss0 = 0.f, s1 = 0.f, ss1 = 0.f;
    const int b0 = qtr * BPQ;

    // ---- prologue: stage batch b0 into buffer 0 ----
    {
        float r0[5];
#pragma unroll
        for (int k = 0; k < 5; ++k)
            r0[k] = (xb[k] >= 0) ? x[b0 * 32768 + xb[k]] : 0.f;
#pragma unroll
        for (int k = 0; k < 5; ++k)
            if (xb[k] != -2) pat[0][tid + k * 256] = (_Float16)r0[k];
    }
    __syncthreads();

    for (int bi = 0; bi < BPQ; ++bi) {
        const int b   = b0 + bi;
        const int cur = bi & 1;

        float r1[5];
        if (bi < BPQ - 1) {
#pragma unroll
            for (int k = 0; k < 5; ++k)
                r1[k] = (xb[k] >= 0) ? x[(b + 1) * 32768 + xb[k]] : 0.f;
        }

        const uint4* pv = (const uint4*)(&pat[cur][f * 72]);
        uint4 u[9];
#pragma unroll
        for (int q = 0; q < 9; ++q) u[q] = pv[q];

        float a0 = bz[0], a1 = bz[1];
#pragma unroll
        for (int q = 0; q < 9; ++q) {
            a0 = DOT2(w2[0][4 * q + 0], bch2(u[q].x), a0);
            a0 = DOT2(w2[0][4 * q + 1], bch2(u[q].y), a0);
            a0 = DOT2(w2[0][4 * q + 2], bch2(u[q].z), a0);
            a0 = DOT2(w2[0][4 * q + 3], bch2(u[q].w), a0);
            a1 = DOT2(w2[1][4 * q + 0], bch2(u[q].x), a1);
            a1 = DOT2(w2[1][4 * q + 1], bch2(u[q].y), a1);
            a1 = DOT2(w2[1][4 * q + 2], bch2(u[q].z), a1);
            a1 = DOT2(w2[1][4 * q + 3], bch2(u[q].w), a1);
        }

        y[(b * Oo + og) * F2 + col]      = a0;
        y[(b * Oo + og + 16) * F2 + col] = a1;
        s0 += a0; ss0 = fmaf(a0, a0, ss0);
        s1 += a1; ss1 = fmaf(a1, a1, ss1);

        if (bi < BPQ - 1) {
#pragma unroll
            for (int k = 0; k < 5; ++k)
                if (xb[k] != -2) pat[cur ^ 1][tid + k * 256] = (_Float16)r1[k];
        }
        __syncthreads();
    }

    // ---- BN partials (primary path only) ----
    if (psum != nullptr) {
#pragma unroll
        for (int d = 8; d >= 1; d >>= 1) {
            s0  += __shfl_down(s0,  d, 16);
            ss0 += __shfl_down(ss0, d, 16);
            s1  += __shfl_down(s1,  d, 16);
            ss1 += __shfl_down(ss1, d, 16);
        }
        if (f == 0) {
            const int slot = blockIdx.x;
            psum[og * SLOTS + slot]          = s0;
            psumsq[og * SLOTS + slot]        = ss0;
            psum[(og + 16) * SLOTS + slot]   = s1;
            psumsq[(og + 16) * SLOTS + slot] = ss1;
        }
    }
}

__global__ __launch_bounds__(256) void bnstats_kernel(
    const float* __restrict__ psum, const float* __restrict__ psumsq,
    const float* __restrict__ gamma, const float* __restrict__ beta,
    float* __restrict__ scsh)
{
    const int o = blockIdx.x;
    const int t = threadIdx.x;
    float s = 0.f, ss = 0.f;
#pragma unroll
    for (int i = 0; i < 4; ++i) {
        s  += psum[o * SLOTS + t + 256 * i];
        ss += psumsq[o * SLOTS + t + 256 * i];
    }
#pragma unroll
    for (int d = 32; d >= 1; d >>= 1) {
        s  += __shfl_down(s, d, 64);
        ss += __shfl_down(ss, d, 64);
    }
    __shared__ float ls[4], lss[4];
    int wv = t >> 6, ln = t & 63;
    if (ln == 0) { ls[wv] = s; lss[wv] = ss; }
    __syncthreads();
    if (t == 0) {
        float S   = (ls[0] + ls[1]) + (ls[2] + ls[3]);
        float SS  = (lss[0] + lss[1]) + (lss[2] + lss[3]);
        float mean = S / (float)NTOT;
        float var  = SS / (float)NTOT - mean * mean;
        float rstd = rsqrtf(var + 1e-5f);
        float scl  = gamma[o] * rstd;
        scsh[o]      = scl;
        scsh[Oo + o] = beta[o] - mean * scl;
    }
}

// ---- fallback stats path (tiny scratch): reduce y directly ----
__global__ __launch_bounds__(256) void bnreduce_y_kernel(
    const float* __restrict__ y, float* __restrict__ seg, float* __restrict__ segsq)
{
    const int o  = blockIdx.x >> 3;
    const int sg = blockIdx.x & 7;
    const int t  = threadIdx.x;
    float s = 0.f, ss = 0.f;
    for (int i = t; i < 4 * 1024; i += 256) {      // 4 batches x 1024 float4
        int b   = sg * 4 + (i >> 10);
        int fof = (i & 1023) * 4;
        float4 v = *(const float4*)(y + (size_t)(b * Oo + o) * F2 + fof);
        s  += (v.x + v.y) + (v.z + v.w);
        ss += v.x * v.x + v.y * v.y + v.z * v.z + v.w * v.w;
    }
#pragma unroll
    for (int d = 32; d >= 1; d >>= 1) {
        s  += __shfl_down(s, d, 64);
        ss += __shfl_down(ss, d, 64);
    }
    __shared__ float ls[4], lss[4];
    int wv = t >> 6, ln = t & 63;
    if (ln == 0) { ls[wv] = s; lss[wv] = ss; }
    __syncthreads();
    if (t == 0) {
        seg[blockIdx.x]   = (ls[0] + ls[1]) + (ls[2] + ls[3]);
        segsq[blockIdx.x] = (lss[0] + lss[1]) + (lss[2] + lss[3]);
    }
}

__global__ __launch_bounds__(256) void bnstats2_kernel(
    const float* __restrict__ seg, const float* __restrict__ segsq,
    const float* __restrict__ gamma, const float* __restrict__ beta,
    float* __restrict__ scsh)
{
    const int t = threadIdx.x;       // 256 = 32 o x 8 segments
    const int o = t >> 3, g = t & 7;
    float v  = seg[t];
    float vv = segsq[t];
#pragma unroll
    for (int d = 4; d >= 1; d >>= 1) {
        v  += __shfl_down(v,  d, 8);
        vv += __shfl_down(vv, d, 8);
    }
    if (g == 0) {
        float mean = v / (float)NTOT;
        float var  = vv / (float)NTOT - mean * mean;
        float rstd = rsqrtf(var + 1e-5f);
        float scl  = gamma[o] * rstd;
        scsh[o]      = scl;
        scsh[Oo + o] = beta[o] - mean * scl;
    }
}

__global__ __launch_bounds__(256) void bnapply_kernel(
    float* __restrict__ y, const float* __restrict__ scsh)
{
    int i = blockIdx.x * 256 + threadIdx.x;    // float4 index
    float4 v = ((const float4*)y)[i];
    int o = (i >> 10) & 31;                    // F2/4 = 1024 float4 per (b,o)
    float scl = scsh[o], sh = scsh[Oo + o];
    v.x = fmaf(v.x, scl, sh);
    v.y = fmaf(v.y, scl, sh);
    v.z = fmaf(v.z, scl, sh);
    v.w = fmaf(v.w, scl, sh);
    ((float4*)y)[i] = v;
}

extern "C" void kernel_launch(void* const* d_in, const int* in_sizes, int n_in,
                              void* d_out, int out_size, void* d_ws, size_t ws_size,
                              hipStream_t stream)
{
    const float* x     = (const float*)d_in[0];
    const float* wgt   = (const float*)d_in[1];
    const float* bias  = (const float*)d_in[2];
    const float* gamma = (const float*)d_in[3];
    const float* beta  = (const float*)d_in[4];
    float* y = (float*)d_out;

    const size_t need_primary = (size_t)(2 * Oo * SLOTS + 2 * Oo) * sizeof(float);

    if (ws_size >= need_primary) {
        float* psum   = (float*)d_ws;               // [Oo][SLOTS]
        float* psumsq = psum + Oo * SLOTS;          // [Oo][SLOTS]
        float* scsh   = psumsq + Oo * SLOTS;        // [2][Oo]
        svconv_kernel<<<GRID, 256, 0, stream>>>(x, wgt, bias, y, psum, psumsq);
        bnstats_kernel<<<Oo, 256, 0, stream>>>(psum, psumsq, gamma, beta, scsh);
        bnapply_kernel<<<NTOT * Oo / 4 / 256, 256, 0, stream>>>(y, scsh);
    } else {
        float* seg   = (float*)d_ws;                // [256]
        float* segsq = seg + 256;                   // [256]
        float* scsh  = segsq + 256;                 // [2][Oo]
        svconv_kernel<<<GRID, 256, 0, stream>>>(x, wgt, bias, y, nullptr, nullptr);
        bnreduce_y_kernel<<<256, 256, 0, stream>>>(y, seg, segsq);
        bnstats2_kernel<<<1, 256, 0, stream>>>(seg, segsq, gamma, beta, scsh);
        bnapply_kernel<<<NTOT * Oo / 4 / 256, 256, 0, stream>>>(y, scsh);
    }
}

// Round 9
// 73.627 us; speedup vs baseline: 1.1288x; 1.0526x over previous
//
#include <hip/hip_runtime.h>

#define Oo    32
#define F2    4096
#define NTILE 256            // pixel tiles of 16
#define OGRP  4              // o-dimension split (8 o's per block)
#define GRID  (NTILE * OGRP) // 1024
#define SLOTS (NTILE * 2)    // per-o partial slots: tile x bh
#define NTOT  (32 * F2)

typedef _Float16 h2 __attribute__((ext_vector_type(2)));
typedef _Float16 h8 __attribute__((ext_vector_type(8)));

#if __has_builtin(__builtin_amdgcn_fdot2)
#define DOT2(a, b, c) __builtin_amdgcn_fdot2((a), (b), (c), false)
#else
__device__ __forceinline__ float DOT2(h2 a, h2 b, float c) {
    return c + (float)a.x * (float)b.x + (float)a.y * (float)b.y;
}
#endif

__device__ __forceinline__ h2 bch2(unsigned u) { return __builtin_bit_cast(h2, u); }

// o-split structure: weights read EXACTLY ONCE chip-wide (round 8's batch
// quartering re-read them 4x -> FETCH 143MB; o-split keeps each (o,p,f) in
// exactly one block). Grid 1024 = (oq:4) x (tile:256) -> 4 blocks/CU,
// 16 waves/CU. Block: 256 thr = (bh:2) x (og:8) x (f:16); thread owns 1 o
// (w2[36] = 36 VGPRs, ~105 total, no spill) and 16 batches of its half.
// Patches: f16, per-half double-buffered LDS, one barrier/iter, next batch
// prefetched into regs during compute (round-3 pipeline, passed post-timing 4x).
// Only x staging is replicated x4 (x = 4MB, trivial).
template <typename YT>
__global__ __launch_bounds__(256) void svconv_kernel(
    const float* __restrict__ x, const float* __restrict__ wgt,
    const float* __restrict__ bias, YT* __restrict__ y,
    float* __restrict__ psum, float* __restrict__ psumsq)
{
    __shared__ __align__(16) _Float16 pat[2][2][16 * 72];  // [bh][buf]

    const int tid  = threadIdx.x;
    const int f    = tid & 15;
    const int og   = (tid >> 4) & 7;
    const int bh   = tid >> 7;
    const int t127 = tid & 127;
    const int tile = blockIdx.x & (NTILE - 1);
    const int oq   = blockIdx.x >> 8;
    const int o    = oq * 8 + og;
    const int fb   = tile * 16;
    const int col  = fb + f;
    const int h    = fb >> 6;
    const int w0   = fb & 63;

    // ---- weights for this thread's single o, packed f16 (read once) ----
    h2 w2[36];
    {
        const float* wp = wgt + (size_t)(o * 72) * F2 + col;
#pragma unroll
        for (int q = 0; q < 36; ++q) {
            float a = wp[(2 * q) * F2];
            float b = wp[(2 * q + 1) * F2];
            h2 t; t.x = (_Float16)a; t.y = (_Float16)b;
            w2[q] = t;
        }
    }
    const float bz = bias[o * F2 + col];

    // ---- patch-fill slots: 128 threads/half stage 1152 elems, 9 each ----
    int xb[9];
#pragma unroll
    for (int k = 0; k < 9; ++k) {
        int e   = t127 + k * 128;
        int pix = e / 72, p = e - pix * 72;
        int c   = p / 9,  r = p - c * 9;
        int kh  = r / 3,  kw = r - kh * 3;
        int gh  = h + kh - 1;
        int gw  = w0 + pix + kw - 1;
        xb[k] = ((unsigned)gh < 64u && (unsigned)gw < 64u)
                    ? (c * 64 + gh) * 64 + gw : -1;
    }

    float s = 0.f, ss = 0.f;
    const int b0 = bh * 16;

    // ---- prologue: stage batch b0 into buffer 0 ----
    {
        float r0[9];
#pragma unroll
        for (int k = 0; k < 9; ++k)
            r0[k] = (xb[k] >= 0) ? x[b0 * 32768 + xb[k]] : 0.f;
#pragma unroll
        for (int k = 0; k < 9; ++k)
            pat[bh][0][t127 + k * 128] = (_Float16)r0[k];
    }
    __syncthreads();

    for (int bi = 0; bi < 16; ++bi) {
        const int b   = b0 + bi;
        const int cur = bi & 1;

        float r1[9];
        if (bi < 15) {
#pragma unroll
            for (int k = 0; k < 9; ++k)
                r1[k] = (xb[k] >= 0) ? x[(b + 1) * 32768 + xb[k]] : 0.f;
        }

        const uint4* pv = (const uint4*)(&pat[bh][cur][f * 72]);
        uint4 u[9];
#pragma unroll
        for (int q = 0; q < 9; ++q) u[q] = pv[q];

        float a0 = bz;
#pragma unroll
        for (int q = 0; q < 9; ++q) {
            a0 = DOT2(w2[4 * q + 0], bch2(u[q].x), a0);
            a0 = DOT2(w2[4 * q + 1], bch2(u[q].y), a0);
            a0 = DOT2(w2[4 * q + 2], bch2(u[q].z), a0);
            a0 = DOT2(w2[4 * q + 3], bch2(u[q].w), a0);
        }

        y[(size_t)(b * Oo + o) * F2 + col] = (YT)a0;
        s += a0; ss = fmaf(a0, a0, ss);

        if (bi < 15) {
#pragma unroll
            for (int k = 0; k < 9; ++k)
                pat[bh][cur ^ 1][t127 + k * 128] = (_Float16)r1[k];
        }
        __syncthreads();
    }

    // ---- BN partials ----
    if (psum != nullptr) {
#pragma unroll
        for (int d = 8; d >= 1; d >>= 1) {
            s  += __shfl_down(s,  d, 16);
            ss += __shfl_down(ss, d, 16);
        }
        if (f == 0) {
            const int slot = tile * 2 + bh;
            psum[o * SLOTS + slot]   = s;
            psumsq[o * SLOTS + slot] = ss;
        }
    }
}

__global__ __launch_bounds__(256) void bnstats_kernel(
    const float* __restrict__ psum, const float* __restrict__ psumsq,
    const float* __restrict__ gamma, const float* __restrict__ beta,
    float* __restrict__ scsh)
{
    const int o = blockIdx.x;
    const int t = threadIdx.x;
    float s  = psum[o * SLOTS + t]   + psum[o * SLOTS + t + 256];
    float ss = psumsq[o * SLOTS + t] + psumsq[o * SLOTS + t + 256];
#pragma unroll
    for (int d = 32; d >= 1; d >>= 1) {
        s  += __shfl_down(s, d, 64);
        ss += __shfl_down(ss, d, 64);
    }
    __shared__ float ls[4], lss[4];
    int wv = t >> 6, ln = t & 63;
    if (ln == 0) { ls[wv] = s; lss[wv] = ss; }
    __syncthreads();
    if (t == 0) {
        float S   = (ls[0] + ls[1]) + (ls[2] + ls[3]);
        float SS  = (lss[0] + lss[1]) + (lss[2] + lss[3]);
        float mean = S / (float)NTOT;
        float var  = SS / (float)NTOT - mean * mean;
        float rstd = rsqrtf(var + 1e-5f);
        float scl  = gamma[o] * rstd;
        scsh[o]      = scl;
        scsh[Oo + o] = beta[o] - mean * scl;
    }
}

// ---- primary apply: read f16 y from ws, write fp32 to d_out ----
__global__ __launch_bounds__(256) void bnapply_f16_kernel(
    const _Float16* __restrict__ yh, const float* __restrict__ scsh,
    float* __restrict__ y)
{
    int i = blockIdx.x * 256 + threadIdx.x;    // 8-element packs; 524288 total
    h8 v = ((const h8*)yh)[i];
    int o = (i >> 9) & 31;                      // e = i*8; o = (e>>12)&31
    float scl = scsh[o], sh = scsh[Oo + o];
    float4 lo, hi;
    lo.x = fmaf((float)v[0], scl, sh);
    lo.y = fmaf((float)v[1], scl, sh);
    lo.z = fmaf((float)v[2], scl, sh);
    lo.w = fmaf((float)v[3], scl, sh);
    hi.x = fmaf((float)v[4], scl, sh);
    hi.y = fmaf((float)v[5], scl, sh);
    hi.z = fmaf((float)v[6], scl, sh);
    hi.w = fmaf((float)v[7], scl, sh);
    ((float4*)y)[2 * i]     = lo;
    ((float4*)y)[2 * i + 1] = hi;
}

// ---- fallback apply: fp32 in place ----
__global__ __launch_bounds__(256) void bnapply_kernel(
    float* __restrict__ y, const float* __restrict__ scsh)
{
    int i = blockIdx.x * 256 + threadIdx.x;    // float4 index
    float4 v = ((const float4*)y)[i];
    int o = (i >> 10) & 31;
    float scl = scsh[o], sh = scsh[Oo + o];
    v.x = fmaf(v.x, scl, sh);
    v.y = fmaf(v.y, scl, sh);
    v.z = fmaf(v.z, scl, sh);
    v.w = fmaf(v.w, scl, sh);
    ((float4*)y)[i] = v;
}

// ---- tiny-scratch stats fallback: reduce y directly ----
__global__ __launch_bounds__(256) void bnreduce_y_kernel(
    const float* __restrict__ y, float* __restrict__ seg, float* __restrict__ segsq)
{
    const int o  = blockIdx.x >> 3;
    const int sg = blockIdx.x & 7;
    const int t  = threadIdx.x;
    float s = 0.f, ss = 0.f;
    for (int i = t; i < 4 * 1024; i += 256) {
        int b   = sg * 4 + (i >> 10);
        int fof = (i & 1023) * 4;
        float4 v = *(const float4*)(y + (size_t)(b * Oo + o) * F2 + fof);
        s  += (v.x + v.y) + (v.z + v.w);
        ss += v.x * v.x + v.y * v.y + v.z * v.z + v.w * v.w;
    }
#pragma unroll
    for (int d = 32; d >= 1; d >>= 1) {
        s  += __shfl_down(s, d, 64);
        ss += __shfl_down(ss, d, 64);
    }
    __shared__ float ls[4], lss[4];
    int wv = t >> 6, ln = t & 63;
    if (ln == 0) { ls[wv] = s; lss[wv] = ss; }
    __syncthreads();
    if (t == 0) {
        seg[blockIdx.x]   = (ls[0] + ls[1]) + (ls[2] + ls[3]);
        segsq[blockIdx.x] = (lss[0] + lss[1]) + (lss[2] + lss[3]);
    }
}

__global__ __launch_bounds__(256) void bnstats2_kernel(
    const float* __restrict__ seg, const float* __restrict__ segsq,
    const float* __restrict__ gamma, const float* __restrict__ beta,
    float* __restrict__ scsh)
{
    const int t = threadIdx.x;
    const int o = t >> 3, g = t & 7;
    float v  = seg[t];
    float vv = segsq[t];
#pragma unroll
    for (int d = 4; d >= 1; d >>= 1) {
        v  += __shfl_down(v,  d, 8);
        vv += __shfl_down(vv, d, 8);
    }
    if (g == 0) {
        float mean = v / (float)NTOT;
        float var  = vv / (float)NTOT - mean * mean;
        float rstd = rsqrtf(var + 1e-5f);
        float scl  = gamma[o] * rstd;
        scsh[o]      = scl;
        scsh[Oo + o] = beta[o] - mean * scl;
    }
}

extern "C" void kernel_launch(void* const* d_in, const int* in_sizes, int n_in,
                              void* d_out, int out_size, void* d_ws, size_t ws_size,
                              hipStream_t stream)
{
    const float* x     = (const float*)d_in[0];
    const float* wgt   = (const float*)d_in[1];
    const float* bias  = (const float*)d_in[2];
    const float* gamma = (const float*)d_in[3];
    const float* beta  = (const float*)d_in[4];
    float* y = (float*)d_out;

    const size_t n_elems    = (size_t)NTOT * Oo;              // 4,194,304
    const size_t yh_bytes   = n_elems * sizeof(_Float16);     // 8 MiB
    const size_t psum_bytes = (size_t)(2 * Oo * SLOTS + 2 * Oo) * sizeof(float);

    if (ws_size >= yh_bytes + psum_bytes) {
        // primary: f16 intermediate y in ws
        _Float16* yh  = (_Float16*)d_ws;
        float* psum   = (float*)((char*)d_ws + yh_bytes);     // [Oo][SLOTS]
        float* psumsq = psum + Oo * SLOTS;
        float* scsh   = psumsq + Oo * SLOTS;                  // [2][Oo]
        svconv_kernel<_Float16><<<GRID, 256, 0, stream>>>(x, wgt, bias, yh, psum, psumsq);
        bnstats_kernel<<<Oo, 256, 0, stream>>>(psum, psumsq, gamma, beta, scsh);
        bnapply_f16_kernel<<<(int)(n_elems / 8 / 256), 256, 0, stream>>>(yh, scsh, y);
    } else if (ws_size >= psum_bytes) {
        // secondary: fp32 y in d_out, partials in ws
        float* psum   = (float*)d_ws;
        float* psumsq = psum + Oo * SLOTS;
        float* scsh   = psumsq + Oo * SLOTS;
        svconv_kernel<float><<<GRID, 256, 0, stream>>>(x, wgt, bias, y, psum, psumsq);
        bnstats_kernel<<<Oo, 256, 0, stream>>>(psum, psumsq, gamma, beta, scsh);
        bnapply_kernel<<<(int)(n_elems / 4 / 256), 256, 0, stream>>>(y, scsh);
    } else {
        // tertiary: tiny scratch — reduce y directly
        float* seg   = (float*)d_ws;                          // [256]
        float* segsq = seg + 256;
        float* scsh  = segsq + 256;
        svconv_kernel<float><<<GRID, 256, 0, stream>>>(x, wgt, bias, y, nullptr, nullptr);
        bnreduce_y_kernel<<<256, 256, 0, stream>>>(y, seg, segsq);
        bnstats2_kernel<<<1, 256, 0, stream>>>(seg, segsq, gamma, beta, scsh);
        bnapply_kernel<<<(int)(n_elems / 4 / 256), 256, 0, stream>>>(y, scsh);
    }
}

// Round 10
// 46.562 us; speedup vs baseline: 1.7849x; 1.5813x over previous
//
#include <hip/hip_runtime.h>

#define Oo    32
#define F2    4096
#define NTILE 256            // pixel tiles of 16
#define GRID  1024           // (oq:4) x (tile:256)
#define SLOTS (NTILE * 2)    // per-o partial slots: tile x bh
#define NTOT  (32 * F2)

typedef _Float16 h2 __attribute__((ext_vector_type(2)));
typedef _Float16 h8 __attribute__((ext_vector_type(8)));

#if __has_builtin(__builtin_amdgcn_fdot2)
#define DOT2(a, b, c) __builtin_amdgcn_fdot2((a), (b), (c), false)
#else
__device__ __forceinline__ float DOT2(h2 a, h2 b, float c) {
    return c + (float)a.x * (float)b.x + (float)a.y * (float)b.y;
}
#endif

__device__ __forceinline__ unsigned pkh2f(float a, float b) {
    h2 t; t.x = (_Float16)a; t.y = (_Float16)b;
    return __builtin_bit_cast(unsigned, t);
}
__device__ __forceinline__ h2 bch2(unsigned u) { return __builtin_bit_cast(h2, u); }

// Round-9 decomposition (weights read once chip-wide; o-split grid; f16-y)
// with the gather fixed: instead of ~2300 scattered scalar loads per
// block-iter (the round-9 bottleneck: ~40 cache-line transactions per wave
// load instr -> ~10k cy/iter in the TA/L1 path), each half stages the RAW
// x tile (24 segs x 18 consecutive floats = 432) with coalesced loads
// (~48 lines), then expands raw->patch f16 pairs through LDS (cheap), into
// the same pat layout the proven dot2 loop reads. Depth-2 register
// prefetch (issue b+4 at iter b), pat+raw double-buffered, 1 barrier/iter,
// fully unrolled so all buffer/set indices are compile-time.
template <typename YT>
__global__ __launch_bounds__(256) void svconv_kernel(
    const float* __restrict__ x, const float* __restrict__ wgt,
    const float* __restrict__ bias, YT* __restrict__ y,
    float* __restrict__ psum, float* __restrict__ psumsq)
{
    __shared__ __align__(16) unsigned patU[2][2][576];  // [bh][buf] h2-pairs
    __shared__ __align__(16) float    raw[2][2][480];   // [bh][buf][24*20]

    const int tid  = threadIdx.x;
    const int f    = tid & 15;
    const int og   = (tid >> 4) & 7;
    const int bh   = tid >> 7;
    const int t127 = tid & 127;
    const int tile = blockIdx.x & (NTILE - 1);
    const int oq   = blockIdx.x >> 8;
    const int o    = oq * 8 + og;
    const int fb   = tile * 16;
    const int col  = fb + f;
    const int h    = fb >> 6;
    const int w0   = fb & 63;

    // ---- weights for this thread's single o, packed f16 (read once) ----
    h2 w2[36];
    {
        const float* wp = wgt + (size_t)(o * 72) * F2 + col;
#pragma unroll
        for (int q = 0; q < 36; ++q) {
            float a = wp[(2 * q) * F2];
            float b = wp[(2 * q + 1) * F2];
            h2 t; t.x = (_Float16)a; t.y = (_Float16)b;
            w2[q] = t;
        }
    }
    const float bz = bias[o * F2 + col];

    // ---- raw-load slots (batch-invariant): s = t127 + k*128 over 480 ----
    // seg = s/20 = (c,kh); j = s%20 -> col w0-1+j (j<18 valid)
    int xoff[4];
#pragma unroll
    for (int k = 0; k < 4; ++k) {
        int s = t127 + k * 128;
        if (s < 480) {
            int seg = s / 20, j = s - seg * 20;
            int c = seg / 3, kh = seg - c * 3;
            int gh = h - 1 + kh, gw = w0 - 1 + j;
            xoff[k] = (j < 18 && (unsigned)gh < 64u && (unsigned)gw < 64u)
                          ? (c * 4096 + gh * 64 + gw) : -1;
        } else xoff[k] = -1;
    }

    // ---- expansion slots (batch-invariant): s = t127 + k*128 over 576 ----
    // s = pix*36 + q; pair p = (2q, 2q+1); raw idx = (c*3+kh)*20 + pix+kw
    int ri0[5], ri1[5];
#pragma unroll
    for (int k = 0; k < 5; ++k) {
        int s = t127 + k * 128;
        if (s < 576) {
            int pix = s / 36, q = s - pix * 36;
            int p0 = 2 * q, p1 = 2 * q + 1;
            int c0 = p0 / 9, r0 = p0 - c0 * 9, kh0 = r0 / 3, kw0 = r0 - kh0 * 3;
            int c1 = p1 / 9, r1 = p1 - c1 * 9, kh1 = r1 / 3, kw1 = r1 - kh1 * 3;
            ri0[k] = (c0 * 3 + kh0) * 20 + pix + kw0;
            ri1[k] = (c1 * 3 + kh1) * 20 + pix + kw1;
        } else { ri0[k] = 0; ri1[k] = 0; }
    }

    float sA[4], sB[4];
    const int b0 = bh * 16;

    auto ISSUE = [&](int b, float* dst) {
#pragma unroll
        for (int k = 0; k < 4; ++k)
            dst[k] = (xoff[k] >= 0) ? x[b * 32768 + xoff[k]] : 0.f;
    };
    auto RAWWR = [&](int rbuf, const float* src) {
#pragma unroll
        for (int k = 0; k < 4; ++k)
            if (k < 3 || t127 < 96) raw[bh][rbuf][t127 + k * 128] = src[k];
    };
    auto EXPAND = [&](int rbuf, int pbuf) {
        const float* rb = &raw[bh][rbuf][0];
#pragma unroll
        for (int k = 0; k < 5; ++k)
            if (k < 4 || t127 < 64)
                patU[bh][pbuf][t127 + k * 128] = pkh2f(rb[ri0[k]], rb[ri1[k]]);
    };

    // ---- prologue: pat[0]=b0, raw[0]=b1, sA=b2 (in flight), sB=b3 ----
    ISSUE(b0, sA); RAWWR(1, sA);
    __syncthreads();
    EXPAND(1, 0);
    ISSUE(b0 + 1, sA); RAWWR(0, sA);
    ISSUE(b0 + 2, sA);
    ISSUE(b0 + 3, sB);
    __syncthreads();

    float s = 0.f, ss = 0.f;
#pragma unroll
    for (int bi = 0; bi < 16; ++bi) {
        const int b   = b0 + bi;
        const int cur  = bi & 1;
        const int rcur = bi & 1;

        const uint4* pv = (const uint4*)&patU[bh][cur][f * 36];
        uint4 u[9];
#pragma unroll
        for (int q = 0; q < 9; ++q) u[q] = pv[q];

        // stage next tiles while dot2 chain runs
        if (bi < 15) EXPAND(rcur, cur ^ 1);                      // b+1 -> pat
        if (bi < 14) RAWWR(rcur ^ 1, (bi & 1) ? sB : sA);        // b+2 -> raw
        if (bi < 12) ISSUE(b0 + bi + 4, (bi & 1) ? sB : sA);     // b+4 -> regs

        float a0 = bz;
#pragma unroll
        for (int q = 0; q < 9; ++q) {
            a0 = DOT2(w2[4 * q + 0], bch2(u[q].x), a0);
            a0 = DOT2(w2[4 * q + 1], bch2(u[q].y), a0);
            a0 = DOT2(w2[4 * q + 2], bch2(u[q].z), a0);
            a0 = DOT2(w2[4 * q + 3], bch2(u[q].w), a0);
        }

        y[(size_t)(b * Oo + o) * F2 + col] = (YT)a0;
        s += a0; ss = fmaf(a0, a0, ss);
        __syncthreads();
    }

    // ---- BN partials ----
    if (psum != nullptr) {
#pragma unroll
        for (int d = 8; d >= 1; d >>= 1) {
            s  += __shfl_down(s,  d, 16);
            ss += __shfl_down(ss, d, 16);
        }
        if (f == 0) {
            const int slot = tile * 2 + bh;
            psum[o * SLOTS + slot]   = s;
            psumsq[o * SLOTS + slot] = ss;
        }
    }
}

__global__ __launch_bounds__(256) void bnstats_kernel(
    const float* __restrict__ psum, const float* __restrict__ psumsq,
    const float* __restrict__ gamma, const float* __restrict__ beta,
    float* __restrict__ scsh)
{
    const int o = blockIdx.x;
    const int t = threadIdx.x;
    float s  = psum[o * SLOTS + t]   + psum[o * SLOTS + t + 256];
    float ss = psumsq[o * SLOTS + t] + psumsq[o * SLOTS + t + 256];
#pragma unroll
    for (int d = 32; d >= 1; d >>= 1) {
        s  += __shfl_down(s, d, 64);
        ss += __shfl_down(ss, d, 64);
    }
    __shared__ float ls[4], lss[4];
    int wv = t >> 6, ln = t & 63;
    if (ln == 0) { ls[wv] = s; lss[wv] = ss; }
    __syncthreads();
    if (t == 0) {
        float S   = (ls[0] + ls[1]) + (ls[2] + ls[3]);
        float SS  = (lss[0] + lss[1]) + (lss[2] + lss[3]);
        float mean = S / (float)NTOT;
        float var  = SS / (float)NTOT - mean * mean;
        float rstd = rsqrtf(var + 1e-5f);
        float scl  = gamma[o] * rstd;
        scsh[o]      = scl;
        scsh[Oo + o] = beta[o] - mean * scl;
    }
}

// ---- primary apply: read f16 y from ws, write fp32 to d_out ----
__global__ __launch_bounds__(256) void bnapply_f16_kernel(
    const _Float16* __restrict__ yh, const float* __restrict__ scsh,
    float* __restrict__ y)
{
    int i = blockIdx.x * 256 + threadIdx.x;    // 8-element packs; 524288 total
    h8 v = ((const h8*)yh)[i];
    int o = (i >> 9) & 31;
    float scl = scsh[o], sh = scsh[Oo + o];
    float4 lo, hi;
    lo.x = fmaf((float)v[0], scl, sh);
    lo.y = fmaf((float)v[1], scl, sh);
    lo.z = fmaf((float)v[2], scl, sh);
    lo.w = fmaf((float)v[3], scl, sh);
    hi.x = fmaf((float)v[4], scl, sh);
    hi.y = fmaf((float)v[5], scl, sh);
    hi.z = fmaf((float)v[6], scl, sh);
    hi.w = fmaf((float)v[7], scl, sh);
    ((float4*)y)[2 * i]     = lo;
    ((float4*)y)[2 * i + 1] = hi;
}

// ---- fallback apply: fp32 in place ----
__global__ __launch_bounds__(256) void bnapply_kernel(
    float* __restrict__ y, const float* __restrict__ scsh)
{
    int i = blockIdx.x * 256 + threadIdx.x;    // float4 index
    float4 v = ((const float4*)y)[i];
    int o = (i >> 10) & 31;
    float scl = scsh[o], sh = scsh[Oo + o];
    v.x = fmaf(v.x, scl, sh);
    v.y = fmaf(v.y, scl, sh);
    v.z = fmaf(v.z, scl, sh);
    v.w = fmaf(v.w, scl, sh);
    ((float4*)y)[i] = v;
}

// ---- tiny-scratch stats fallback: reduce y directly ----
__global__ __launch_bounds__(256) void bnreduce_y_kernel(
    const float* __restrict__ y, float* __restrict__ seg, float* __restrict__ segsq)
{
    const int o  = blockIdx.x >> 3;
    const int sg = blockIdx.x & 7;
    const int t  = threadIdx.x;
    float s = 0.f, ss = 0.f;
    for (int i = t; i < 4 * 1024; i += 256) {
        int b   = sg * 4 + (i >> 10);
        int fof = (i & 1023) * 4;
        float4 v = *(const float4*)(y + (size_t)(b * Oo + o) * F2 + fof);
        s  += (v.x + v.y) + (v.z + v.w);
        ss += v.x * v.x + v.y * v.y + v.z * v.z + v.w * v.w;
    }
#pragma unroll
    for (int d = 32; d >= 1; d >>= 1) {
        s  += __shfl_down(s, d, 64);
        ss += __shfl_down(ss, d, 64);
    }
    __shared__ float ls[4], lss[4];
    int wv = t >> 6, ln = t & 63;
    if (ln == 0) { ls[wv] = s; lss[wv] = ss; }
    __syncthreads();
    if (t == 0) {
        seg[blockIdx.x]   = (ls[0] + ls[1]) + (ls[2] + ls[3]);
        segsq[blockIdx.x] = (lss[0] + lss[1]) + (lss[2] + lss[3]);
    }
}

__global__ __launch_bounds__(256) void bnstats2_kernel(
    const float* __restrict__ seg, const float* __restrict__ segsq,
    const float* __restrict__ gamma, const float* __restrict__ beta,
    float* __restrict__ scsh)
{
    const int t = threadIdx.x;
    const int o = t >> 3, g = t & 7;
    float v  = seg[t];
    float vv = segsq[t];
#pragma unroll
    for (int d = 4; d >= 1; d >>= 1) {
        v  += __shfl_down(v,  d, 8);
        vv += __shfl_down(vv, d, 8);
    }
    if (g == 0) {
        float mean = v / (float)NTOT;
        float var  = vv / (float)NTOT - mean * mean;
        float rstd = rsqrtf(var + 1e-5f);
        float scl  = gamma[o] * rstd;
        scsh[o]      = scl;
        scsh[Oo + o] = beta[o] - mean * scl;
    }
}

extern "C" void kernel_launch(void* const* d_in, const int* in_sizes, int n_in,
                              void* d_out, int out_size, void* d_ws, size_t ws_size,
                              hipStream_t stream)
{
    const float* x     = (const float*)d_in[0];
    const float* wgt   = (const float*)d_in[1];
    const float* bias  = (const float*)d_in[2];
    const float* gamma = (const float*)d_in[3];
    const float* beta  = (const float*)d_in[4];
    float* y = (float*)d_out;

    const size_t n_elems    = (size_t)NTOT * Oo;              // 4,194,304
    const size_t yh_bytes   = n_elems * sizeof(_Float16);     // 8 MiB
    const size_t psum_bytes = (size_t)(2 * Oo * SLOTS + 2 * Oo) * sizeof(float);

    if (ws_size >= yh_bytes + psum_bytes) {
        // primary: f16 intermediate y in ws
        _Float16* yh  = (_Float16*)d_ws;
        float* psum   = (float*)((char*)d_ws + yh_bytes);     // [Oo][SLOTS]
        float* psumsq = psum + Oo * SLOTS;
        float* scsh   = psumsq + Oo * SLOTS;                  // [2][Oo]
        svconv_kernel<_Float16><<<GRID, 256, 0, stream>>>(x, wgt, bias, yh, psum, psumsq);
        bnstats_kernel<<<Oo, 256, 0, stream>>>(psum, psumsq, gamma, beta, scsh);
        bnapply_f16_kernel<<<(int)(n_elems / 8 / 256), 256, 0, stream>>>(yh, scsh, y);
    } else if (ws_size >= psum_bytes) {
        // secondary: fp32 y in d_out, partials in ws
        float* psum   = (float*)d_ws;
        float* psumsq = psum + Oo * SLOTS;
        float* scsh   = psumsq + Oo * SLOTS;
        svconv_kernel<float><<<GRID, 256, 0, stream>>>(x, wgt, bias, y, psum, psumsq);
        bnstats_kernel<<<Oo, 256, 0, stream>>>(psum, psumsq, gamma, beta, scsh);
        bnapply_kernel<<<(int)(n_elems / 4 / 256), 256, 0, stream>>>(y, scsh);
    } else {
        // tertiary: tiny scratch — reduce y directly
        float* seg   = (float*)d_ws;                          // [256]
        float* segsq = seg + 256;
        float* scsh  = segsq + 256;
        svconv_kernel<float><<<GRID, 256, 0, stream>>>(x, wgt, bias, y, nullptr, nullptr);
        bnreduce_y_kernel<<<256, 256, 0, stream>>>(y, seg, segsq);
        bnstats2_kernel<<<1, 256, 0, stream>>>(seg, segsq, gamma, beta, scsh);
        bnapply_kernel<<<(int)(n_elems / 4 / 256), 256, 0, stream>>>(y, scsh);
    }
}

// Round 11
// 45.078 us; speedup vs baseline: 1.8437x; 1.0329x over previous
//
#include <hip/hip_runtime.h>

#define Oo    32
#define F2    4096
#define NTILE 256            // pixel tiles of 16
#define GRID  1024           // (oq:4) x (tile:256)
#define SLOTS (NTILE * 2)    // per-o partial slots: tile x bh
#define NTOT  (32 * F2)

typedef _Float16 h2 __attribute__((ext_vector_type(2)));
typedef _Float16 h8 __attribute__((ext_vector_type(8)));

#if __has_builtin(__builtin_amdgcn_fdot2)
#define DOT2(a, b, c) __builtin_amdgcn_fdot2((a), (b), (c), false)
#else
__device__ __forceinline__ float DOT2(h2 a, h2 b, float c) {
    return c + (float)a.x * (float)b.x + (float)a.y * (float)b.y;
}
#endif

__device__ __forceinline__ unsigned pkh2f(float a, float b) {
    h2 t; t.x = (_Float16)a; t.y = (_Float16)b;
    return __builtin_bit_cast(unsigned, t);
}
__device__ __forceinline__ h2 bch2(unsigned u) { return __builtin_bit_cast(h2, u); }

// Round-10 structure (coalesced raw-x staging + LDS expand + o-split grid,
// weights read once chip-wide, f16 intermediate y) with the batch loop
// processed TWO batches per iteration: 8 barrier iters instead of 16, and two
// interleaved dot2 accumulator chains (dependent ops >=4cy apart -> dep
// latency fully hidden at issue rate). Pipeline: EXPAND pair t+1 (raw->pat),
// RAWWR pair t+2 (regs->raw), ISSUE pair t+3 (global->regs) each iteration;
// all buffer indices compile-time (full unroll). Fragment reads per-q
// (uA[q],uB[q]) to keep VGPR ~95 (reading 18 uint4 up front would cost ~136
// regs -> 3 waves/SIMD).
template <typename YT>
__global__ __launch_bounds__(256) void svconv_kernel(
    const float* __restrict__ x, const float* __restrict__ wgt,
    const float* __restrict__ bias, YT* __restrict__ y,
    float* __restrict__ psum, float* __restrict__ psumsq)
{
    __shared__ __align__(16) unsigned patU[2][2][2][576];  // [bh][buf][bat]
    __shared__ __align__(16) float    raw[2][2][2][480];   // [bh][buf][bat]

    const int tid  = threadIdx.x;
    const int f    = tid & 15;
    const int og   = (tid >> 4) & 7;
    const int bh   = tid >> 7;
    const int t127 = tid & 127;
    const int tile = blockIdx.x & (NTILE - 1);
    const int oq   = blockIdx.x >> 8;
    const int o    = oq * 8 + og;
    const int fb   = tile * 16;
    const int col  = fb + f;
    const int h    = fb >> 6;
    const int w0   = fb & 63;

    // ---- weights for this thread's single o, packed f16 (read once) ----
    h2 w2[36];
    {
        const float* wp = wgt + (size_t)(o * 72) * F2 + col;
#pragma unroll
        for (int q = 0; q < 36; ++q) {
            float a = wp[(2 * q) * F2];
            float b = wp[(2 * q + 1) * F2];
            h2 t; t.x = (_Float16)a; t.y = (_Float16)b;
            w2[q] = t;
        }
    }
    const float bz = bias[o * F2 + col];

    // ---- raw-load slots (batch-invariant): s = t127 + k*128 over 480 ----
    int xoff[4];
#pragma unroll
    for (int k = 0; k < 4; ++k) {
        int s = t127 + k * 128;
        if (s < 480) {
            int seg = s / 20, j = s - seg * 20;
            int c = seg / 3, kh = seg - c * 3;
            int gh = h - 1 + kh, gw = w0 - 1 + j;
            xoff[k] = (j < 18 && (unsigned)gh < 64u && (unsigned)gw < 64u)
                          ? (c * 4096 + gh * 64 + gw) : -1;
        } else xoff[k] = -1;
    }

    // ---- expansion slots (batch-invariant): s = t127 + k*128 over 576 ----
    int ri0[5], ri1[5];
#pragma unroll
    for (int k = 0; k < 5; ++k) {
        int s = t127 + k * 128;
        if (s < 576) {
            int pix = s / 36, q = s - pix * 36;
            int p0 = 2 * q, p1 = 2 * q + 1;
            int c0 = p0 / 9, r0 = p0 - c0 * 9, kh0 = r0 / 3, kw0 = r0 - kh0 * 3;
            int c1 = p1 / 9, r1 = p1 - c1 * 9, kh1 = r1 / 3, kw1 = r1 - kh1 * 3;
            ri0[k] = (c0 * 3 + kh0) * 20 + pix + kw0;
            ri1[k] = (c1 * 3 + kh1) * 20 + pix + kw1;
        } else { ri0[k] = 0; ri1[k] = 0; }
    }

    float sA[8];                 // one pair in flight: [batA 0..3 | batB 4..7]
    const int b0 = bh * 16;

    auto ISSUE = [&](int pr) {          // load pair pr into sA
        const int ba = b0 + 2 * pr;
#pragma unroll
        for (int k = 0; k < 4; ++k) {
            sA[k]     = (xoff[k] >= 0) ? x[ba * 32768 + xoff[k]]       : 0.f;
            sA[4 + k] = (xoff[k] >= 0) ? x[(ba + 1) * 32768 + xoff[k]] : 0.f;
        }
    };
    auto RAWWR = [&](int rbuf) {        // sA -> raw[rbuf]
#pragma unroll
        for (int k = 0; k < 4; ++k)
            if (k < 3 || t127 < 96) {
                raw[bh][rbuf][0][t127 + k * 128] = sA[k];
                raw[bh][rbuf][1][t127 + k * 128] = sA[4 + k];
            }
    };
    auto EXPAND = [&](int rbuf, int pbuf) {
        const float* r0 = &raw[bh][rbuf][0][0];
        const float* r1 = &raw[bh][rbuf][1][0];
#pragma unroll
        for (int k = 0; k < 5; ++k)
            if (k < 4 || t127 < 64) {
                patU[bh][pbuf][0][t127 + k * 128] = pkh2f(r0[ri0[k]], r0[ri1[k]]);
                patU[bh][pbuf][1][t127 + k * 128] = pkh2f(r1[ri0[k]], r1[ri1[k]]);
            }
    };

    // ---- prologue: pat0=pair0, raw0=pair1, sA=pair2 in flight ----
    ISSUE(0); RAWWR(1);
    __syncthreads();
    EXPAND(1, 0);
    ISSUE(1); RAWWR(0);
    ISSUE(2);
    __syncthreads();

    float s = 0.f, ss = 0.f;
#pragma unroll
    for (int t = 0; t < 8; ++t) {
        const int pb = t & 1;

        // staging for future pairs (overlaps this iter's compute)
        if (t < 7) EXPAND(t & 1, pb ^ 1);      // pair t+1 -> pat
        if (t < 6) RAWWR((t + 1) & 1);         // pair t+2 -> raw
        if (t < 5) ISSUE(t + 3);               // pair t+3 -> regs

        // compute pair t: two interleaved accumulator chains
        const uint4* pvA = (const uint4*)&patU[bh][pb][0][f * 36];
        const uint4* pvB = (const uint4*)&patU[bh][pb][1][f * 36];
        float a0 = bz, a1 = bz;
#pragma unroll
        for (int q = 0; q < 9; ++q) {
            uint4 xA = pvA[q], xB = pvB[q];
            a0 = DOT2(w2[4 * q + 0], bch2(xA.x), a0);
            a1 = DOT2(w2[4 * q + 0], bch2(xB.x), a1);
            a0 = DOT2(w2[4 * q + 1], bch2(xA.y), a0);
            a1 = DOT2(w2[4 * q + 1], bch2(xB.y), a1);
            a0 = DOT2(w2[4 * q + 2], bch2(xA.z), a0);
            a1 = DOT2(w2[4 * q + 2], bch2(xB.z), a1);
            a0 = DOT2(w2[4 * q + 3], bch2(xA.w), a0);
            a1 = DOT2(w2[4 * q + 3], bch2(xB.w), a1);
        }

        const int ba = b0 + 2 * t;
        y[(size_t)(ba * Oo + o) * F2 + col]       = (YT)a0;
        y[(size_t)((ba + 1) * Oo + o) * F2 + col] = (YT)a1;
        s += a0 + a1;
        ss = fmaf(a0, a0, ss);
        ss = fmaf(a1, a1, ss);
        __syncthreads();
    }

    // ---- BN partials ----
    if (psum != nullptr) {
#pragma unroll
        for (int d = 8; d >= 1; d >>= 1) {
            s  += __shfl_down(s,  d, 16);
            ss += __shfl_down(ss, d, 16);
        }
        if (f == 0) {
            const int slot = tile * 2 + bh;
            psum[o * SLOTS + slot]   = s;
            psumsq[o * SLOTS + slot] = ss;
        }
    }
}

__global__ __launch_bounds__(256) void bnstats_kernel(
    const float* __restrict__ psum, const float* __restrict__ psumsq,
    const float* __restrict__ gamma, const float* __restrict__ beta,
    float* __restrict__ scsh)
{
    const int o = blockIdx.x;
    const int t = threadIdx.x;
    float s  = psum[o * SLOTS + t]   + psum[o * SLOTS + t + 256];
    float ss = psumsq[o * SLOTS + t] + psumsq[o * SLOTS + t + 256];
#pragma unroll
    for (int d = 32; d >= 1; d >>= 1) {
        s  += __shfl_down(s, d, 64);
        ss += __shfl_down(ss, d, 64);
    }
    __shared__ float ls[4], lss[4];
    int wv = t >> 6, ln = t & 63;
    if (ln == 0) { ls[wv] = s; lss[wv] = ss; }
    __syncthreads();
    if (t == 0) {
        float S   = (ls[0] + ls[1]) + (ls[2] + ls[3]);
        float SS  = (lss[0] + lss[1]) + (lss[2] + lss[3]);
        float mean = S / (float)NTOT;
        float var  = SS / (float)NTOT - mean * mean;
        float rstd = rsqrtf(var + 1e-5f);
        float scl  = gamma[o] * rstd;
        scsh[o]      = scl;
        scsh[Oo + o] = beta[o] - mean * scl;
    }
}

// ---- primary apply: read f16 y from ws, write fp32 to d_out ----
__global__ __launch_bounds__(256) void bnapply_f16_kernel(
    const _Float16* __restrict__ yh, const float* __restrict__ scsh,
    float* __restrict__ y)
{
    int i = blockIdx.x * 256 + threadIdx.x;    // 8-element packs; 524288 total
    h8 v = ((const h8*)yh)[i];
    int o = (i >> 9) & 31;
    float scl = scsh[o], sh = scsh[Oo + o];
    float4 lo, hi;
    lo.x = fmaf((float)v[0], scl, sh);
    lo.y = fmaf((float)v[1], scl, sh);
    lo.z = fmaf((float)v[2], scl, sh);
    lo.w = fmaf((float)v[3], scl, sh);
    hi.x = fmaf((float)v[4], scl, sh);
    hi.y = fmaf((float)v[5], scl, sh);
    hi.z = fmaf((float)v[6], scl, sh);
    hi.w = fmaf((float)v[7], scl, sh);
    ((float4*)y)[2 * i]     = lo;
    ((float4*)y)[2 * i + 1] = hi;
}

// ---- fallback apply: fp32 in place ----
__global__ __launch_bounds__(256) void bnapply_kernel(
    float* __restrict__ y, const float* __restrict__ scsh)
{
    int i = blockIdx.x * 256 + threadIdx.x;    // float4 index
    float4 v = ((const float4*)y)[i];
    int o = (i >> 10) & 31;
    float scl = scsh[o], sh = scsh[Oo + o];
    v.x = fmaf(v.x, scl, sh);
    v.y = fmaf(v.y, scl, sh);
    v.z = fmaf(v.z, scl, sh);
    v.w = fmaf(v.w, scl, sh);
    ((float4*)y)[i] = v;
}

// ---- tiny-scratch stats fallback: reduce y directly ----
__global__ __launch_bounds__(256) void bnreduce_y_kernel(
    const float* __restrict__ y, float* __restrict__ seg, float* __restrict__ segsq)
{
    const int o  = blockIdx.x >> 3;
    const int sg = blockIdx.x & 7;
    const int t  = threadIdx.x;
    float s = 0.f, ss = 0.f;
    for (int i = t; i < 4 * 1024; i += 256) {
        int b   = sg * 4 + (i >> 10);
        int fof = (i & 1023) * 4;
        float4 v = *(const float4*)(y + (size_t)(b * Oo + o) * F2 + fof);
        s  += (v.x + v.y) + (v.z + v.w);
        ss += v.x * v.x + v.y * v.y + v.z * v.z + v.w * v.w;
    }
#pragma unroll
    for (int d = 32; d >= 1; d >>= 1) {
        s  += __shfl_down(s, d, 64);
        ss += __shfl_down(ss, d, 64);
    }
    __shared__ float ls[4], lss[4];
    int wv = t >> 6, ln = t & 63;
    if (ln == 0) { ls[wv] = s; lss[wv] = ss; }
    __syncthreads();
    if (t == 0) {
        seg[blockIdx.x]   = (ls[0] + ls[1]) + (ls[2] + ls[3]);
        segsq[blockIdx.x] = (lss[0] + lss[1]) + (lss[2] + lss[3]);
    }
}

__global__ __launch_bounds__(256) void bnstats2_kernel(
    const float* __restrict__ seg, const float* __restrict__ segsq,
    const float* __restrict__ gamma, const float* __restrict__ beta,
    float* __restrict__ scsh)
{
    const int t = threadIdx.x;
    const int o = t >> 3, g = t & 7;
    float v  = seg[t];
    float vv = segsq[t];
#pragma unroll
    for (int d = 4; d >= 1; d >>= 1) {
        v  += __shfl_down(v,  d, 8);
        vv += __shfl_down(vv, d, 8);
    }
    if (g == 0) {
        float mean = v / (float)NTOT;
        float var  = vv / (float)NTOT - mean * mean;
        float rstd = rsqrtf(var + 1e-5f);
        float scl  = gamma[o] * rstd;
        scsh[o]      = scl;
        scsh[Oo + o] = beta[o] - mean * scl;
    }
}

extern "C" void kernel_launch(void* const* d_in, const int* in_sizes, int n_in,
                              void* d_out, int out_size, void* d_ws, size_t ws_size,
                              hipStream_t stream)
{
    const float* x     = (const float*)d_in[0];
    const float* wgt   = (const float*)d_in[1];
    const float* bias  = (const float*)d_in[2];
    const float* gamma = (const float*)d_in[3];
    const float* beta  = (const float*)d_in[4];
    float* y = (float*)d_out;

    const size_t n_elems    = (size_t)NTOT * Oo;              // 4,194,304
    const size_t yh_bytes   = n_elems * sizeof(_Float16);     // 8 MiB
    const size_t psum_bytes = (size_t)(2 * Oo * SLOTS + 2 * Oo) * sizeof(float);

    if (ws_size >= yh_bytes + psum_bytes) {
        // primary: f16 intermediate y in ws
        _Float16* yh  = (_Float16*)d_ws;
        float* psum   = (float*)((char*)d_ws + yh_bytes);     // [Oo][SLOTS]
        float* psumsq = psum + Oo * SLOTS;
        float* scsh   = psumsq + Oo * SLOTS;                  // [2][Oo]
        svconv_kernel<_Float16><<<GRID, 256, 0, stream>>>(x, wgt, bias, yh, psum, psumsq);
        bnstats_kernel<<<Oo, 256, 0, stream>>>(psum, psumsq, gamma, beta, scsh);
        bnapply_f16_kernel<<<(int)(n_elems / 8 / 256), 256, 0, stream>>>(yh, scsh, y);
    } else if (ws_size >= psum_bytes) {
        // secondary: fp32 y in d_out, partials in ws
        float* psum   = (float*)d_ws;
        float* psumsq = psum + Oo * SLOTS;
        float* scsh   = psumsq + Oo * SLOTS;
        svconv_kernel<float><<<GRID, 256, 0, stream>>>(x, wgt, bias, y, psum, psumsq);
        bnstats_kernel<<<Oo, 256, 0, stream>>>(psum, psumsq, gamma, beta, scsh);
        bnapply_kernel<<<(int)(n_elems / 4 / 256), 256, 0, stream>>>(y, scsh);
    } else {
        // tertiary: tiny scratch — reduce y directly
        float* seg   = (float*)d_ws;                          // [256]
        float* segsq = seg + 256;
        float* scsh  = segsq + 256;
        svconv_kernel<float><<<GRID, 256, 0, stream>>>(x, wgt, bias, y, nullptr, nullptr);
        bnreduce_y_kernel<<<256, 256, 0, stream>>>(y, seg, segsq);
        bnstats2_kernel<<<1, 256, 0, stream>>>(seg, segsq, gamma, beta, scsh);
        bnapply_kernel<<<(int)(n_elems / 4 / 256), 256, 0, stream>>>(y, scsh);
    }
}

// Round 12
// 43.919 us; speedup vs baseline: 1.8923x; 1.0264x over previous
//
#include <hip/hip_runtime.h>

#define Oo    32
#define F2    4096
#define NTILE 256            // pixel tiles of 16
#define GRID  512            // (oq:2) x (tile:256) -> 2 blocks/CU
#define SLOTS (NTILE * 2)    // per-o partial slots: tile x bh
#define NTOT  (32 * F2)

typedef _Float16 h2 __attribute__((ext_vector_type(2)));
typedef _Float16 h8 __attribute__((ext_vector_type(8)));

#if __has_builtin(__builtin_amdgcn_fdot2)
#define DOT2(a, b, c) __builtin_amdgcn_fdot2((a), (b), (c), false)
#else
__device__ __forceinline__ float DOT2(h2 a, h2 b, float c) {
    return c + (float)a.x * (float)b.x + (float)a.y * (float)b.y;
}
#endif

__device__ __forceinline__ unsigned pkh2f(float a, float b) {
    h2 t; t.x = (_Float16)a; t.y = (_Float16)b;
    return __builtin_bit_cast(unsigned, t);
}
__device__ __forceinline__ h2 bch2(unsigned u) { return __builtin_bit_cast(h2, u); }

// Round-11 structure with the LDS-instruction count halved (the measured
// bound: ~56 LDS instrs/wave-iter x 16 waves/CU serialized on the LDS pipe).
// (1) Each thread computes 2 o's (o0=oq*16+og, o1=o0+8): pat b128 reads are
//     og-broadcast, so half the waves issue them -> total LDS instrs/CU halve.
//     Grid 512 = (oq:2)x(tile:256), block (bh:2)x(og:8)x(f:16), 2 blocks/CU.
// (2) Aligned vector staging: raw row slots reordered as
//     [gw=w0..w0+15 | w0-1, w0+16, w0+17 | pad]; interior threads (g<4) load
//     one 16B-aligned float4/batch (always in-bounds: gw in [w0,w0+15]) and
//     store one ds_write_b128; extras thread (g==4) does 3 masked scalars.
//     ISSUE 8->2 instrs, RAWWR 8->2 per pair. EXPAND identical (remapped ri).
// Pipeline/barriers byte-identical to round 11 (passed post-timing 2x).
template <typename YT>
__global__ __launch_bounds__(256) void svconv_kernel(
    const float* __restrict__ x, const float* __restrict__ wgt,
    const float* __restrict__ bias, YT* __restrict__ y,
    float* __restrict__ psum, float* __restrict__ psumsq)
{
    __shared__ __align__(16) unsigned patU[2][2][2][576];  // [bh][buf][bat]
    __shared__ __align__(16) float4   raw4[2][2][2][120];  // [bh][buf][bat][24*5]

    const int tid  = threadIdx.x;
    const int f    = tid & 15;
    const int og   = (tid >> 4) & 7;
    const int bh   = tid >> 7;
    const int t127 = tid & 127;
    const int tile = blockIdx.x & (NTILE - 1);
    const int oq   = blockIdx.x >> 8;          // 0..1
    const int o0   = oq * 16 + og;
    const int o1   = o0 + 8;
    const int fb   = tile * 16;
    const int col  = fb + f;
    const int h    = fb >> 6;
    const int w0   = fb & 63;

    // ---- weights for 2 o's, packed f16 (each weight read once chip-wide) ----
    h2 w2[2][36];
    float bz[2];
#pragma unroll
    for (int j = 0; j < 2; ++j) {
        const int o = j ? o1 : o0;
        const float* wp = wgt + (size_t)(o * 72) * F2 + col;
#pragma unroll
        for (int q = 0; q < 36; ++q) {
            float a = wp[(2 * q) * F2];
            float b = wp[(2 * q + 1) * F2];
            h2 t; t.x = (_Float16)a; t.y = (_Float16)b;
            w2[j][q] = t;
        }
        bz[j] = bias[o * F2 + col];
    }

    // ---- raw staging roles: t127 = seg*5 + g; seg=(c,kh) of 24, g=0..4 ----
    const bool staged = (t127 < 120);
    const int  seg = t127 / 5, g = t127 - 5 * (t127 / 5);
    const int  c_  = seg / 3, kh_ = seg - 3 * (seg / 3);
    const int  gh  = h - 1 + kh_;
    const bool ghOK = ((unsigned)gh < 64u);
    const int  vbase = c_ * 4096 + gh * 64 + w0 + 4 * g;   // g<4: 16B-aligned
    int exo[3];                                             // g==4 extras
    {
        int gws[3] = { w0 - 1, w0 + 16, w0 + 17 };
#pragma unroll
        for (int k = 0; k < 3; ++k)
            exo[k] = (ghOK && (unsigned)gws[k] < 64u)
                         ? (c_ * 4096 + gh * 64 + gws[k]) : -1;
    }

    // ---- expansion slots: s = t127 + k*128 over 576 pat pairs ----
    // raw slot for gw: d = gw - w0; d in [0,16) -> d; d==-1 -> 16; d>=16 -> d+1
    int ri0[5], ri1[5];
#pragma unroll
    for (int k = 0; k < 5; ++k) {
        int s = t127 + k * 128;
        if (s < 576) {
            int pix = s / 36, q = s - pix * 36;
            int p0 = 2 * q, p1 = 2 * q + 1;
            int c0 = p0 / 9, r0 = p0 - c0 * 9, kh0 = r0 / 3, kw0 = r0 - kh0 * 3;
            int c1 = p1 / 9, r1 = p1 - c1 * 9, kh1 = r1 / 3, kw1 = r1 - kh1 * 3;
            int d0 = pix + kw0 - 1, d1 = pix + kw1 - 1;
            int ns0 = (d0 < 0) ? 16 : ((d0 < 16) ? d0 : d0 + 1);
            int ns1 = (d1 < 0) ? 16 : ((d1 < 16) ? d1 : d1 + 1);
            ri0[k] = (c0 * 3 + kh0) * 20 + ns0;
            ri1[k] = (c1 * 3 + kh1) * 20 + ns1;
        } else { ri0[k] = 0; ri1[k] = 0; }
    }

    float4 v0, v1;               // one pair in flight
    const int b0 = bh * 16;

    auto ISSUE = [&](int pr) {
        const int ba = b0 + 2 * pr;
        if (staged) {
            if (g < 4) {
                if (ghOK) {
                    v0 = *(const float4*)(x + ba * 32768 + vbase);
                    v1 = *(const float4*)(x + (ba + 1) * 32768 + vbase);
                } else {
                    v0 = make_float4(0.f, 0.f, 0.f, 0.f);
                    v1 = v0;
                }
            } else {
                v0.x = (exo[0] >= 0) ? x[ba * 32768 + exo[0]] : 0.f;
                v0.y = (exo[1] >= 0) ? x[ba * 32768 + exo[1]] : 0.f;
                v0.z = (exo[2] >= 0) ? x[ba * 32768 + exo[2]] : 0.f;
                v0.w = 0.f;
                v1.x = (exo[0] >= 0) ? x[(ba + 1) * 32768 + exo[0]] : 0.f;
                v1.y = (exo[1] >= 0) ? x[(ba + 1) * 32768 + exo[1]] : 0.f;
                v1.z = (exo[2] >= 0) ? x[(ba + 1) * 32768 + exo[2]] : 0.f;
                v1.w = 0.f;
            }
        }
    };
    auto RAWWR = [&](int rbuf) {         // one b128 per batch
        if (staged) {
            raw4[bh][rbuf][0][t127] = v0;
            raw4[bh][rbuf][1][t127] = v1;
        }
    };
    auto EXPAND = [&](int rbuf, int pbuf) {
        const float* rb0 = (const float*)&raw4[bh][rbuf][0][0];
        const float* rb1 = (const float*)&raw4[bh][rbuf][1][0];
#pragma unroll
        for (int k = 0; k < 5; ++k)
            if (k < 4 || t127 < 64) {
                patU[bh][pbuf][0][t127 + k * 128] = pkh2f(rb0[ri0[k]], rb0[ri1[k]]);
                patU[bh][pbuf][1][t127 + k * 128] = pkh2f(rb1[ri0[k]], rb1[ri1[k]]);
            }
    };

    // ---- prologue: pat0=pair0, raw0=pair1, regs=pair2 ----
    ISSUE(0); RAWWR(1);
    __syncthreads();
    EXPAND(1, 0);
    ISSUE(1); RAWWR(0);
    ISSUE(2);
    __syncthreads();

    float s0 = 0.f, ss0 = 0.f, s1 = 0.f, ss1 = 0.f;
#pragma unroll
    for (int t = 0; t < 8; ++t) {
        const int pb = t & 1;

        if (t < 7) EXPAND(t & 1, pb ^ 1);      // pair t+1 -> pat
        if (t < 6) RAWWR((t + 1) & 1);         // pair t+2 -> raw
        if (t < 5) ISSUE(t + 3);               // pair t+3 -> regs

        const uint4* pvA = (const uint4*)&patU[bh][pb][0][f * 36];
        const uint4* pvB = (const uint4*)&patU[bh][pb][1][f * 36];
        float a00 = bz[0], a01 = bz[0], a10 = bz[1], a11 = bz[1];
#pragma unroll
        for (int q = 0; q < 9; ++q) {
            uint4 xA = pvA[q], xB = pvB[q];
            a00 = DOT2(w2[0][4 * q + 0], bch2(xA.x), a00);
            a01 = DOT2(w2[0][4 * q + 0], bch2(xB.x), a01);
            a10 = DOT2(w2[1][4 * q + 0], bch2(xA.x), a10);
            a11 = DOT2(w2[1][4 * q + 0], bch2(xB.x), a11);
            a00 = DOT2(w2[0][4 * q + 1], bch2(xA.y), a00);
            a01 = DOT2(w2[0][4 * q + 1], bch2(xB.y), a01);
            a10 = DOT2(w2[1][4 * q + 1], bch2(xA.y), a10);
            a11 = DOT2(w2[1][4 * q + 1], bch2(xB.y), a11);
            a00 = DOT2(w2[0][4 * q + 2], bch2(xA.z), a00);
            a01 = DOT2(w2[0][4 * q + 2], bch2(xB.z), a01);
            a10 = DOT2(w2[1][4 * q + 2], bch2(xA.z), a10);
            a11 = DOT2(w2[1][4 * q + 2], bch2(xB.z), a11);
            a00 = DOT2(w2[0][4 * q + 3], bch2(xA.w), a00);
            a01 = DOT2(w2[0][4 * q + 3], bch2(xB.w), a01);
            a10 = DOT2(w2[1][4 * q + 3], bch2(xA.w), a10);
            a11 = DOT2(w2[1][4 * q + 3], bch2(xB.w), a11);
        }

        const int ba = b0 + 2 * t;
        y[(size_t)(ba * Oo + o0) * F2 + col]       = (YT)a00;
        y[(size_t)(ba * Oo + o1) * F2 + col]       = (YT)a10;
        y[(size_t)((ba + 1) * Oo + o0) * F2 + col] = (YT)a01;
        y[(size_t)((ba + 1) * Oo + o1) * F2 + col] = (YT)a11;
        s0 += a00 + a01; ss0 = fmaf(a00, a00, ss0); ss0 = fmaf(a01, a01, ss0);
        s1 += a10 + a11; ss1 = fmaf(a10, a10, ss1); ss1 = fmaf(a11, a11, ss1);
        __syncthreads();
    }

    // ---- BN partials ----
    if (psum != nullptr) {
#pragma unroll
        for (int d = 8; d >= 1; d >>= 1) {
            s0  += __shfl_down(s0,  d, 16);
            ss0 += __shfl_down(ss0, d, 16);
            s1  += __shfl_down(s1,  d, 16);
            ss1 += __shfl_down(ss1, d, 16);
        }
        if (f == 0) {
            const int slot = tile * 2 + bh;
            psum[o0 * SLOTS + slot]   = s0;
            psumsq[o0 * SLOTS + slot] = ss0;
            psum[o1 * SLOTS + slot]   = s1;
            psumsq[o1 * SLOTS + slot] = ss1;
        }
    }
}

__global__ __launch_bounds__(256) void bnstats_kernel(
    const float* __restrict__ psum, const float* __restrict__ psumsq,
    const float* __restrict__ gamma, const float* __restrict__ beta,
    float* __restrict__ scsh)
{
    const int o = blockIdx.x;
    const int t = threadIdx.x;
    float s  = psum[o * SLOTS + t]   + psum[o * SLOTS + t + 256];
    float ss = psumsq[o * SLOTS + t] + psumsq[o * SLOTS + t + 256];
#pragma unroll
    for (int d = 32; d >= 1; d >>= 1) {
        s  += __shfl_down(s, d, 64);
        ss += __shfl_down(ss, d, 64);
    }
    __shared__ float ls[4], lss[4];
    int wv = t >> 6, ln = t & 63;
    if (ln == 0) { ls[wv] = s; lss[wv] = ss; }
    __syncthreads();
    if (t == 0) {
        float S   = (ls[0] + ls[1]) + (ls[2] + ls[3]);
        float SS  = (lss[0] + lss[1]) + (lss[2] + lss[3]);
        float mean = S / (float)NTOT;
        float var  = SS / (float)NTOT - mean * mean;
        float rstd = rsqrtf(var + 1e-5f);
        float scl  = gamma[o] * rstd;
        scsh[o]      = scl;
        scsh[Oo + o] = beta[o] - mean * scl;
    }
}

// ---- primary apply: read f16 y from ws, write fp32 to d_out ----
__global__ __launch_bounds__(256) void bnapply_f16_kernel(
    const _Float16* __restrict__ yh, const float* __restrict__ scsh,
    float* __restrict__ y)
{
    int i = blockIdx.x * 256 + threadIdx.x;    // 8-element packs; 524288 total
    h8 v = ((const h8*)yh)[i];
    int o = (i >> 9) & 31;
    float scl = scsh[o], sh = scsh[Oo + o];
    float4 lo, hi;
    lo.x = fmaf((float)v[0], scl, sh);
    lo.y = fmaf((float)v[1], scl, sh);
    lo.z = fmaf((float)v[2], scl, sh);
    lo.w = fmaf((float)v[3], scl, sh);
    hi.x = fmaf((float)v[4], scl, sh);
    hi.y = fmaf((float)v[5], scl, sh);
    hi.z = fmaf((float)v[6], scl, sh);
    hi.w = fmaf((float)v[7], scl, sh);
    ((float4*)y)[2 * i]     = lo;
    ((float4*)y)[2 * i + 1] = hi;
}

// ---- fallback apply: fp32 in place ----
__global__ __launch_bounds__(256) void bnapply_kernel(
    float* __restrict__ y, const float* __restrict__ scsh)
{
    int i = blockIdx.x * 256 + threadIdx.x;    // float4 index
    float4 v = ((const float4*)y)[i];
    int o = (i >> 10) & 31;
    float scl = scsh[o], sh = scsh[Oo + o];
    v.x = fmaf(v.x, scl, sh);
    v.y = fmaf(v.y, scl, sh);
    v.z = fmaf(v.z, scl, sh);
    v.w = fmaf(v.w, scl, sh);
    ((float4*)y)[i] = v;
}

// ---- tiny-scratch stats fallback: reduce y directly ----
__global__ __launch_bounds__(256) void bnreduce_y_kernel(
    const float* __restrict__ y, float* __restrict__ seg, float* __restrict__ segsq)
{
    const int o  = blockIdx.x >> 3;
    const int sg = blockIdx.x & 7;
    const int t  = threadIdx.x;
    float s = 0.f, ss = 0.f;
    for (int i = t; i < 4 * 1024; i += 256) {
        int b   = sg * 4 + (i >> 10);
        int fof = (i & 1023) * 4;
        float4 v = *(const float4*)(y + (size_t)(b * Oo + o) * F2 + fof);
        s  += (v.x + v.y) + (v.z + v.w);
        ss += v.x * v.x + v.y * v.y + v.z * v.z + v.w * v.w;
    }
#pragma unroll
    for (int d = 32; d >= 1; d >>= 1) {
        s  += __shfl_down(s, d, 64);
        ss += __shfl_down(ss, d, 64);
    }
    __shared__ float ls[4], lss[4];
    int wv = t >> 6, ln = t & 63;
    if (ln == 0) { ls[wv] = s; lss[wv] = ss; }
    __syncthreads();
    if (t == 0) {
        seg[blockIdx.x]   = (ls[0] + ls[1]) + (ls[2] + ls[3]);
        segsq[blockIdx.x] = (lss[0] + lss[1]) + (lss[2] + lss[3]);
    }
}

__global__ __launch_bounds__(256) void bnstats2_kernel(
    const float* __restrict__ seg, const float* __restrict__ segsq,
    const float* __restrict__ gamma, const float* __restrict__ beta,
    float* __restrict__ scsh)
{
    const int t = threadIdx.x;
    const int o = t >> 3, g = t & 7;
    float v  = seg[t];
    float vv = segsq[t];
#pragma unroll
    for (int d = 4; d >= 1; d >>= 1) {
        v  += __shfl_down(v,  d, 8);
        vv += __shfl_down(vv, d, 8);
    }
    if (g == 0) {
        float mean = v / (float)NTOT;
        float var  = vv / (float)NTOT - mean * mean;
        float rstd = rsqrtf(var + 1e-5f);
        float scl  = gamma[o] * rstd;
        scsh[o]      = scl;
        scsh[Oo + o] = beta[o] - mean * scl;
    }
}

extern "C" void kernel_launch(void* const* d_in, const int* in_sizes, int n_in,
                              void* d_out, int out_size, void* d_ws, size_t ws_size,
                              hipStream_t stream)
{
    const float* x     = (const float*)d_in[0];
    const float* wgt   = (const float*)d_in[1];
    const float* bias  = (const float*)d_in[2];
    const float* gamma = (const float*)d_in[3];
    const float* beta  = (const float*)d_in[4];
    float* y = (float*)d_out;

    const size_t n_elems    = (size_t)NTOT * Oo;              // 4,194,304
    const size_t yh_bytes   = n_elems * sizeof(_Float16);     // 8 MiB
    const size_t psum_bytes = (size_t)(2 * Oo * SLOTS + 2 * Oo) * sizeof(float);

    if (ws_size >= yh_bytes + psum_bytes) {
        // primary: f16 intermediate y in ws
        _Float16* yh  = (_Float16*)d_ws;
        float* psum   = (float*)((char*)d_ws + yh_bytes);     // [Oo][SLOTS]
        float* psumsq = psum + Oo * SLOTS;
        float* scsh   = psumsq + Oo * SLOTS;                  // [2][Oo]
        svconv_kernel<_Float16><<<GRID, 256, 0, stream>>>(x, wgt, bias, yh, psum, psumsq);
        bnstats_kernel<<<Oo, 256, 0, stream>>>(psum, psumsq, gamma, beta, scsh);
        bnapply_f16_kernel<<<(int)(n_elems / 8 / 256), 256, 0, stream>>>(yh, scsh, y);
    } else if (ws_size >= psum_bytes) {
        // secondary: fp32 y in d_out, partials in ws
        float* psum   = (float*)d_ws;
        float* psumsq = psum + Oo * SLOTS;
        float* scsh   = psumsq + Oo * SLOTS;
        svconv_kernel<float><<<GRID, 256, 0, stream>>>(x, wgt, bias, y, psum, psumsq);
        bnstats_kernel<<<Oo, 256, 0, stream>>>(psum, psumsq, gamma, beta, scsh);
        bnapply_kernel<<<(int)(n_elems / 4 / 256), 256, 0, stream>>>(y, scsh);
    } else {
        // tertiary: tiny scratch — reduce y directly
        float* seg   = (float*)d_ws;                          // [256]
        float* segsq = seg + 256;
        float* scsh  = segsq + 256;
        svconv_kernel<float><<<GRID, 256, 0, stream>>>(x, wgt, bias, y, nullptr, nullptr);
        bnreduce_y_kernel<<<256, 256, 0, stream>>>(y, seg, segsq);
        bnstats2_kernel<<<1, 256, 0, stream>>>(seg, segsq, gamma, beta, scsh);
        bnapply_kernel<<<(int)(n_elems / 4 / 256), 256, 0, stream>>>(y, scsh);
    }
}